// Round 9
// baseline (2042.773 us; speedup 1.0000x reference)
//
#include <hip/hip_runtime.h>
#include <hip/hip_bf16.h>
#include <cmath>

constexpr int NB = 4096;   // batch
constexpr int NH = 1024;   // hidden
constexpr int NE = 8;      // experts
constexpr int NF = 4096;   // dff
constexpr int NG = 512;    // gate hidden (H/2)
constexpr float THRESH = 0.1f;

// Established (rounds 0-8):
//   ALL inputs: f32, C-order, setup_inputs positional order (sizes verified).
//   d_out: FLOAT32, [output (B,H) | gate_weights (B,E)].
//   ws_size >= ~67 MB (guard-verified).

typedef float  f32x4  __attribute__((ext_vector_type(4)));
typedef __bf16 bf16x8 __attribute__((ext_vector_type(8)));

__device__ __forceinline__ float silu_f(float v) { return v / (1.f + expf(-v)); }

__global__ void k_sentinel(float* out, float code)
{
    if (threadIdx.x == 0 && blockIdx.x == 0) out[0] = code;
}

// ---------------------------------------------------------------------------
// Gate GEMM: hidden = silu(x @ gate_w1 + gate_b1)   (f32 exact)
// ---------------------------------------------------------------------------
__global__ __launch_bounds__(256) void k_gate(
    const float* __restrict__ x, const float* __restrict__ w1,
    const float* __restrict__ b1, float* __restrict__ hidden)
{
    __shared__ float As[16][68];   // [k][m]
    __shared__ float Bs[16][64];   // [k][n]
    const int tid = threadIdx.x;
    const int r0 = blockIdx.y * 64, c0 = blockIdx.x * 64;
    const int tx = tid & 15, ty = tid >> 4;
    float acc[4][4] = {};
    for (int k0 = 0; k0 < NH; k0 += 16) {
#pragma unroll
        for (int i = 0; i < 4; i++) {
            int e = tid + i * 256;
            int m = e >> 4, kk = e & 15;
            As[kk][m] = x[(size_t)(r0 + m) * NH + k0 + kk];
        }
#pragma unroll
        for (int i = 0; i < 4; i++) {
            int e = tid + i * 256;
            int kk = e >> 6, n = e & 63;
            Bs[kk][n] = w1[(size_t)(k0 + kk) * NG + c0 + n];
        }
        __syncthreads();
#pragma unroll
        for (int kk = 0; kk < 16; kk++) {
            f32x4 a = *(const f32x4*)&As[kk][ty * 4];
            f32x4 b = *(const f32x4*)&Bs[kk][tx * 4];
#pragma unroll
            for (int i = 0; i < 4; i++)
#pragma unroll
                for (int j = 0; j < 4; j++)
                    acc[i][j] = fmaf(a[i], b[j], acc[i][j]);
        }
        __syncthreads();
    }
#pragma unroll
    for (int i = 0; i < 4; i++) {
        int row = r0 + ty * 4 + i;
        f32x4 o;
#pragma unroll
        for (int j = 0; j < 4; j++)
            o[j] = silu_f(acc[i][j] + b1[c0 + tx * 4 + j]);
        *(f32x4*)&hidden[(size_t)row * NG + c0 + tx * 4] = o;
    }
}

// ---------------------------------------------------------------------------
// Router: logits -> softmax -> top2 -> threshold -> per-expert slot lists
// gate_weights written f32.
// ---------------------------------------------------------------------------
__global__ __launch_bounds__(64) void k_router(
    const float* __restrict__ hidden, const float* __restrict__ w2,
    const float* __restrict__ b2, float* __restrict__ gw_out,
    int* __restrict__ count, int* __restrict__ slot_row,
    float* __restrict__ slot_w, float* __restrict__ row_total,
    int* __restrict__ row_fired)
{
    const int r = blockIdx.x;
    const int l = threadIdx.x;
    float pe[NE] = {};
    for (int k = l; k < NG; k += 64) {
        float h = hidden[(size_t)r * NG + k];
        const float* wr = w2 + (size_t)k * NE;
#pragma unroll
        for (int e = 0; e < NE; e++) pe[e] += h * wr[e];
    }
#pragma unroll
    for (int e = 0; e < NE; e++) {
#pragma unroll
        for (int m = 1; m < 64; m <<= 1) pe[e] += __shfl_xor(pe[e], m);
    }
    float logit[NE];
    float mx = -1e30f;
#pragma unroll
    for (int e = 0; e < NE; e++) { logit[e] = pe[e] + b2[e]; mx = fmaxf(mx, logit[e]); }
    float w[NE], s = 0.f;
#pragma unroll
    for (int e = 0; e < NE; e++) { w[e] = expf(logit[e] - mx); s += w[e]; }
    float inv = 1.f / s;
#pragma unroll
    for (int e = 0; e < NE; e++) w[e] *= inv;
    if (l < NE) gw_out[(size_t)r * NE + l] = w[l];

    // top-2 (ties -> lower index, matching lax.top_k)
    int i1 = 0; float v1 = w[0];
#pragma unroll
    for (int e = 1; e < NE; e++) if (w[e] > v1) { v1 = w[e]; i1 = e; }
    int i2 = -1; float v2 = -1.f;
#pragma unroll
    for (int e = 0; e < NE; e++) if (e != i1 && w[e] > v2) { v2 = w[e]; i2 = e; }

    bool k1 = v1 > THRESH, k2 = v2 > THRESH;
    float total = (k1 ? v1 : 0.f) + (k2 ? v2 : 0.f);
    if (l == 0) {
        row_total[r] = total;
        row_fired[r] = (total > 0.f) ? 1 : 0;
        if (k1) { int p = atomicAdd(&count[i1], 1); slot_row[i1 * NB + p] = r; slot_w[i1 * NB + p] = v1; }
        if (k2) { int p = atomicAdd(&count[i2], 1); slot_row[i2 * NB + p] = r; slot_w[i2 * NB + p] = v2; }
    }
}

// ---------------------------------------------------------------------------
// Routed MFMA GEMM for ONE expert (W/bias pre-offset by host).
// AK==0: gather f32 rows of x via slot_row.  AK==1: A = bf16 rows, row = slot.
// W: f32 C-order [Kd x N].  ACT: silu.
// OM: 0 = store bf16 slot rows (+bias), 1 = weighted f32 atomicAdd.
// Tile 128x128, BK=64, 4 waves, 16x16x32 bf16 MFMA, XOR-swizzled LDS.
// ---------------------------------------------------------------------------
template<int AK, int ACT, int OM>
__global__ __launch_bounds__(256) void k_moe_gemm(
    const float* __restrict__ Af32, const __bf16* __restrict__ Abf, int lda,
    const float* __restrict__ W, const float* __restrict__ bias,
    __bf16* __restrict__ outB, float* __restrict__ outF,
    int N, int Kd, int e,
    const int* __restrict__ count,
    const int* __restrict__ slot_row, const float* __restrict__ slot_w)
{
    const int cnt = count[e];
    const int row0 = blockIdx.y * 128;
    if (row0 >= cnt) return;
    const int n0 = blockIdx.x * 128;
    const int tid = threadIdx.x;
    const int lane = tid & 63, wid = tid >> 6;
    const int wm = (wid >> 1) * 64, wn = (wid & 1) * 64;

    __shared__ __align__(16) unsigned char sA[128 * 128];  // [m][k] bf16, swizzled
    __shared__ __align__(16) unsigned char sB[128 * 128];  // [n][k] bf16, swizzled

    f32x4 acc[4][4];
#pragma unroll
    for (int mi = 0; mi < 4; mi++)
#pragma unroll
        for (int ni = 0; ni < 4; ni++)
            acc[mi][ni] = (f32x4){0.f, 0.f, 0.f, 0.f};

    for (int k0 = 0; k0 < Kd; k0 += 64) {
        // ---- stage A (128 slot-rows x 64 k) ----
#pragma unroll
        for (int i = 0; i < 4; i++) {
            int idx = tid + i * 256;
            int m = idx >> 3, kg = idx & 7;
            int slot = row0 + m;
            bf16x8 v;
            if (slot < cnt) {
                if (AK == 0) {
                    int ri = slot_row[e * NB + slot];
                    const float* p = Af32 + (size_t)ri * lda + k0 + kg * 8;
                    f32x4 f0 = *(const f32x4*)p;
                    f32x4 f1 = *(const f32x4*)(p + 4);
#pragma unroll
                    for (int j = 0; j < 4; j++) { v[j] = (__bf16)f0[j]; v[4 + j] = (__bf16)f1[j]; }
                } else {
                    v = *(const bf16x8*)(Abf + (size_t)slot * lda + k0 + kg * 8);
                }
            } else {
#pragma unroll
                for (int j = 0; j < 8; j++) v[j] = (__bf16)0.f;
            }
            *(bf16x8*)(sA + m * 128 + ((kg * 16) ^ ((m & 7) << 4))) = v;
        }
        // ---- stage B (64 k x 128 n), f32 -> bf16, to [n][k] ----
#pragma unroll
        for (int i = 0; i < 4; i++) {
            int kg = (tid >> 6) + ((i & 1) << 2);   // 0..7
            int n  = (tid & 63) + ((i >> 1) << 6);  // 0..127
            bf16x8 v;
#pragma unroll
            for (int kk = 0; kk < 8; kk++)
                v[kk] = (__bf16)W[(size_t)(k0 + kg * 8 + kk) * N + n0 + n];
            *(bf16x8*)(sB + n * 128 + ((kg * 16) ^ ((n & 7) << 4))) = v;
        }
        __syncthreads();
        // ---- MFMA: two K=32 steps ----
#pragma unroll
        for (int ks = 0; ks < 2; ks++) {
            bf16x8 af[4], bfr[4];
            const int kb = ks * 64 + ((lane >> 4) << 4);
#pragma unroll
            for (int mi = 0; mi < 4; mi++) {
                int row = wm + mi * 16 + (lane & 15);
                af[mi] = *(const bf16x8*)(sA + row * 128 + (kb ^ ((row & 7) << 4)));
            }
#pragma unroll
            for (int ni = 0; ni < 4; ni++) {
                int row = wn + ni * 16 + (lane & 15);
                bfr[ni] = *(const bf16x8*)(sB + row * 128 + (kb ^ ((row & 7) << 4)));
            }
#pragma unroll
            for (int mi = 0; mi < 4; mi++)
#pragma unroll
                for (int ni = 0; ni < 4; ni++)
                    acc[mi][ni] = __builtin_amdgcn_mfma_f32_16x16x32_bf16(
                        af[mi], bfr[ni], acc[mi][ni], 0, 0, 0);
        }
        __syncthreads();
    }

    // ---- epilogue ----
    const int q = lane >> 4, cl = lane & 15;
#pragma unroll
    for (int mi = 0; mi < 4; mi++) {
#pragma unroll
        for (int r = 0; r < 4; r++) {
            int srow = row0 + wm + mi * 16 + q * 4 + r;
            if (srow >= cnt) continue;
            if (OM == 0) {
#pragma unroll
                for (int ni = 0; ni < 4; ni++) {
                    int col = n0 + wn + ni * 16 + cl;
                    float vv = acc[mi][ni][r] + bias[col];
                    if (ACT) vv = silu_f(vv);
                    outB[(size_t)srow * N + col] = (__bf16)vv;
                }
            } else {
                int grow = slot_row[e * NB + srow];
                float wsl = slot_w[e * NB + srow];
#pragma unroll
                for (int ni = 0; ni < 4; ni++) {
                    int col = n0 + wn + ni * 16 + cl;
                    atomicAdd(&outF[(size_t)grow * NH + col], wsl * acc[mi][ni][r]);
                }
            }
        }
    }
}

// ---------------------------------------------------------------------------
// Finalize: out = fired ? alpha*(combined/total) + (1-alpha)*x : x   (f32 out)
// ---------------------------------------------------------------------------
__global__ __launch_bounds__(256) void k_final(
    const float* __restrict__ combined, const float* __restrict__ x,
    const float* __restrict__ row_total, const int* __restrict__ row_fired,
    const float* __restrict__ blend, float* __restrict__ out)
{
    int idx = blockIdx.x * 256 + threadIdx.x;  // one thread per 4 elements
    int r = idx >> 8;
    int c = (idx & 255) << 2;
    float alpha = 1.f / (1.f + expf(-blend[0]));
    f32x4 cb = *(const f32x4*)(combined + (size_t)r * NH + c);
    f32x4 xv = *(const f32x4*)(x + (size_t)r * NH + c);
    int fired = row_fired[r];
    float inv_t = fired ? (1.f / row_total[r]) : 0.f;
    f32x4 o;
#pragma unroll
    for (int j = 0; j < 4; j++)
        o[j] = fired ? (alpha * (cb[j] * inv_t) + (1.f - alpha) * xv[j]) : xv[j];
    *(f32x4*)&out[(size_t)r * NH + c] = o;
}

// ---------------------------------------------------------------------------
extern "C" void kernel_launch(void* const* d_in, const int* in_sizes, int n_in,
                              void* d_out, int out_size, void* d_ws, size_t ws_size,
                              hipStream_t stream)
{
    float* out_main = (float*)d_out;                      // (B,H) f32, chunk 0
    float* gw_out   = (float*)d_out + (size_t)NB * NH;    // (B,E) f32, chunk 1

    static const long long EXP[11] = {
        (long long)NB * NH, (long long)NH * NG, NG, (long long)NG * NE, NE,
        (long long)NE * NH * NF, (long long)NE * NF,
        (long long)NE * NF * NH, (long long)NE * NH,
        (long long)NE * NH * NH, 1
    };
    bool ok = (n_in == 11);
    if (ok)
        for (int i = 0; i < 11; i++)
            if ((long long)in_sizes[i] != EXP[i]) { ok = false; break; }
    if (!ok) {
        k_sentinel<<<1, 1, 0, stream>>>((float*)d_out, 2000.f + n_in);
        return;
    }

    const float* x    = (const float*)d_in[0];
    const float* gw1  = (const float*)d_in[1];
    const float* gb1  = (const float*)d_in[2];
    const float* gw2  = (const float*)d_in[3];
    const float* gb2  = (const float*)d_in[4];
    const float* ew1  = (const float*)d_in[5];
    const float* eb1  = (const float*)d_in[6];
    const float* ew2  = (const float*)d_in[7];
    const float* eb2  = (const float*)d_in[8];
    const float* pw   = (const float*)d_in[9];
    const float* blnd = (const float*)d_in[10];

    // ---- workspace (~64.4 MiB, under proven >=67 MB bound) ----
    size_t need = 0;
    size_t off_count  = need;   need += 256;
    size_t off_hidden = need;   need += (size_t)NB * NG * 4;   // 8 MiB
    size_t off_srow   = need;   need += (size_t)NE * NB * 4;   // 128 KiB
    size_t off_sw     = need;   need += (size_t)NE * NB * 4;   // 128 KiB
    size_t off_total  = need;   need += (size_t)NB * 4;
    size_t off_fired  = need;   need += (size_t)NB * 4;
    size_t off_comb   = need;   need += (size_t)NB * NH * 4;   // 16 MiB
    size_t off_h1     = need;   need += (size_t)NB * NF * 2;   // 32 MiB
    size_t off_h2     = need;   need += (size_t)NB * NH * 2;   // 8 MiB
    if (ws_size < need) {
        k_sentinel<<<1, 1, 0, stream>>>((float*)d_out,
                                        1000.f + (float)(ws_size >> 20));
        return;
    }
    char* ws = (char*)d_ws;
    int*   count     = (int*)(ws + off_count);
    float* hidden    = (float*)(ws + off_hidden);
    int*   slot_row  = (int*)(ws + off_srow);
    float* slot_w    = (float*)(ws + off_sw);
    float* row_total = (float*)(ws + off_total);
    int*   row_fired = (int*)(ws + off_fired);
    float* combined  = (float*)(ws + off_comb);
    __bf16* H1       = (__bf16*)(ws + off_h1);
    __bf16* H2       = (__bf16*)(ws + off_h2);

    hipMemsetAsync(count, 0, 256, stream);
    hipMemsetAsync(combined, 0, (size_t)NB * NH * 4, stream);

    k_gate<<<dim3(NG / 64, NB / 64), 256, 0, stream>>>(x, gw1, gb1, hidden);
    k_router<<<dim3(NB), 64, 0, stream>>>(hidden, gw2, gb2, gw_out,
                                          count, slot_row, slot_w, row_total, row_fired);

    for (int e = 0; e < NE; e++) {
        // FFN1: H1[slot] = silu(x[slot_row] @ exp_w1[e] + exp_b1[e])
        k_moe_gemm<0, 1, 0><<<dim3(NF / 128, NB / 128), 256, 0, stream>>>(
            x, nullptr, NH, ew1 + (size_t)e * NH * NF, eb1 + (size_t)e * NF,
            H1, nullptr, NF, NH, e, count, slot_row, slot_w);
        // FFN2: H2[slot] = H1[slot] @ exp_w2[e] + exp_b2[e]
        k_moe_gemm<1, 0, 0><<<dim3(NH / 128, NB / 128), 256, 0, stream>>>(
            nullptr, H1, NF, ew2 + (size_t)e * NF * NH, eb2 + (size_t)e * NH,
            H2, nullptr, NH, NF, e, count, slot_row, slot_w);
        // PROJ: combined[grow] += slot_w * (H2[slot] @ proj_w[e])
        k_moe_gemm<1, 0, 1><<<dim3(NH / 128, NB / 128), 256, 0, stream>>>(
            nullptr, H2, NH, pw + (size_t)e * NH * NH, nullptr,
            nullptr, combined, NH, NH, e, count, slot_row, slot_w);
    }

    k_final<<<dim3(NB * NH / 1024), 256, 0, stream>>>(combined, x, row_total,
                                                      row_fired, blnd, out_main);
}

// Round 10
// 653.277 us; speedup vs baseline: 3.1270x; 3.1270x over previous
//
#include <hip/hip_runtime.h>
#include <hip/hip_bf16.h>
#include <cmath>

constexpr int NB = 4096;   // batch
constexpr int NH = 1024;   // hidden
constexpr int NE = 8;      // experts
constexpr int NF = 4096;   // dff
constexpr int NG = 512;    // gate hidden (H/2)
constexpr float THRESH = 0.1f;

// Established (rounds 0-9):
//   ALL inputs: f32, C-order, positional order (sizes verified each call).
//   d_out: FLOAT32, [output (B,H) | gate_weights (B,E)].
//   ws_size >= ~67 MB proven; likely >= ~105 MB (R1-R3 ran 104 MiB layouts).

typedef float  f32x4  __attribute__((ext_vector_type(4)));
typedef __bf16 bf16x8 __attribute__((ext_vector_type(8)));

__device__ __forceinline__ float silu_f(float v) { return v / (1.f + expf(-v)); }

__global__ void k_sentinel(float* out, float code)
{
    if (threadIdx.x == 0 && blockIdx.x == 0) out[0] = code;
}

// ---------------------------------------------------------------------------
// Gate GEMM: hidden = silu(x @ gate_w1 + gate_b1)   (f32 exact)
// ---------------------------------------------------------------------------
__global__ __launch_bounds__(256) void k_gate(
    const float* __restrict__ x, const float* __restrict__ w1,
    const float* __restrict__ b1, float* __restrict__ hidden)
{
    __shared__ float As[16][68];   // [k][m]
    __shared__ float Bs[16][64];   // [k][n]
    const int tid = threadIdx.x;
    const int r0 = blockIdx.y * 64, c0 = blockIdx.x * 64;
    const int tx = tid & 15, ty = tid >> 4;
    float acc[4][4] = {};
    for (int k0 = 0; k0 < NH; k0 += 16) {
#pragma unroll
        for (int i = 0; i < 4; i++) {
            int e = tid + i * 256;
            int m = e >> 4, kk = e & 15;
            As[kk][m] = x[(size_t)(r0 + m) * NH + k0 + kk];
        }
#pragma unroll
        for (int i = 0; i < 4; i++) {
            int e = tid + i * 256;
            int kk = e >> 6, n = e & 63;
            Bs[kk][n] = w1[(size_t)(k0 + kk) * NG + c0 + n];
        }
        __syncthreads();
#pragma unroll
        for (int kk = 0; kk < 16; kk++) {
            f32x4 a = *(const f32x4*)&As[kk][ty * 4];
            f32x4 b = *(const f32x4*)&Bs[kk][tx * 4];
#pragma unroll
            for (int i = 0; i < 4; i++)
#pragma unroll
                for (int j = 0; j < 4; j++)
                    acc[i][j] = fmaf(a[i], b[j], acc[i][j]);
        }
        __syncthreads();
    }
#pragma unroll
    for (int i = 0; i < 4; i++) {
        int row = r0 + ty * 4 + i;
        f32x4 o;
#pragma unroll
        for (int j = 0; j < 4; j++)
            o[j] = silu_f(acc[i][j] + b1[c0 + tx * 4 + j]);
        *(f32x4*)&hidden[(size_t)row * NG + c0 + tx * 4] = o;
    }
}

// ---------------------------------------------------------------------------
// Router: logits -> softmax -> top2 -> threshold -> per-expert slot lists
// ---------------------------------------------------------------------------
__global__ __launch_bounds__(64) void k_router(
    const float* __restrict__ hidden, const float* __restrict__ w2,
    const float* __restrict__ b2, float* __restrict__ gw_out,
    int* __restrict__ count, int* __restrict__ slot_row,
    float* __restrict__ slot_w, float* __restrict__ row_total,
    int* __restrict__ row_fired)
{
    const int r = blockIdx.x;
    const int l = threadIdx.x;
    float pe[NE] = {};
    for (int k = l; k < NG; k += 64) {
        float h = hidden[(size_t)r * NG + k];
        const float* wr = w2 + (size_t)k * NE;
#pragma unroll
        for (int e = 0; e < NE; e++) pe[e] += h * wr[e];
    }
#pragma unroll
    for (int e = 0; e < NE; e++) {
#pragma unroll
        for (int m = 1; m < 64; m <<= 1) pe[e] += __shfl_xor(pe[e], m);
    }
    float logit[NE];
    float mx = -1e30f;
#pragma unroll
    for (int e = 0; e < NE; e++) { logit[e] = pe[e] + b2[e]; mx = fmaxf(mx, logit[e]); }
    float w[NE], s = 0.f;
#pragma unroll
    for (int e = 0; e < NE; e++) { w[e] = expf(logit[e] - mx); s += w[e]; }
    float inv = 1.f / s;
#pragma unroll
    for (int e = 0; e < NE; e++) w[e] *= inv;
    if (l < NE) gw_out[(size_t)r * NE + l] = w[l];

    int i1 = 0; float v1 = w[0];
#pragma unroll
    for (int e = 1; e < NE; e++) if (w[e] > v1) { v1 = w[e]; i1 = e; }
    int i2 = -1; float v2 = -1.f;
#pragma unroll
    for (int e = 0; e < NE; e++) if (e != i1 && w[e] > v2) { v2 = w[e]; i2 = e; }

    bool k1 = v1 > THRESH, k2 = v2 > THRESH;
    float total = (k1 ? v1 : 0.f) + (k2 ? v2 : 0.f);
    if (l == 0) {
        row_total[r] = total;
        row_fired[r] = (total > 0.f) ? 1 : 0;
        if (k1) { int p = atomicAdd(&count[i1], 1); slot_row[i1 * NB + p] = r; slot_w[i1 * NB + p] = v1; }
        if (k2) { int p = atomicAdd(&count[i2], 1); slot_row[i2 * NB + p] = r; slot_w[i2 * NB + p] = v2; }
    }
}

__global__ void k_offsets(const int* __restrict__ count, int* __restrict__ offs)
{
    if (threadIdx.x == 0 && blockIdx.x == 0) {
        int s = 0;
        for (int e = 0; e < NE; e++) { offs[e] = s; s += count[e]; }
    }
}

// ---------------------------------------------------------------------------
// Routed MFMA GEMM, batched across experts via blockIdx.z (e = e_base + z).
// AK==0: gather f32 x rows via slot_row.  AK==1: A = bf16 compacted rows
// (row = offs[e] + slot).  W = Wbase + e*wstride (f32 C-order [Kd x N]).
// ACT: silu.  OM: 0 = store bf16 compacted rows (+bias), 1 = weighted f32
// atomicAdd into outF (the f32 d_out) via slot_row/slot_w.
// Tile 128x128, BK=64, 4 waves, 16x16x32 bf16 MFMA, XOR-swizzled LDS.
// ---------------------------------------------------------------------------
template<int AK, int ACT, int OM>
__global__ __launch_bounds__(256) void k_moe_gemm(
    const float* __restrict__ Af32, const __bf16* __restrict__ Abf, int lda,
    const float* __restrict__ Wbase, size_t wstride,
    const float* __restrict__ bias_base, int bias_stride,
    __bf16* __restrict__ outB, float* __restrict__ outF,
    int N, int Kd, int e_base,
    const int* __restrict__ count, const int* __restrict__ offs,
    const int* __restrict__ slot_row, const float* __restrict__ slot_w)
{
    const int e = e_base + blockIdx.z;
    const int cnt = count[e];
    const int row0 = blockIdx.y * 128;
    if (row0 >= cnt) return;
    const int off = offs[e];
    const float* W = Wbase + (size_t)e * wstride;
    const int n0 = blockIdx.x * 128;
    const int tid = threadIdx.x;
    const int lane = tid & 63, wid = tid >> 6;
    const int wm = (wid >> 1) * 64, wn = (wid & 1) * 64;

    __shared__ __align__(16) unsigned char sA[128 * 128];  // [m][k] bf16, swizzled
    __shared__ __align__(16) unsigned char sB[128 * 128];  // [n][k] bf16, swizzled

    f32x4 acc[4][4];
#pragma unroll
    for (int mi = 0; mi < 4; mi++)
#pragma unroll
        for (int ni = 0; ni < 4; ni++)
            acc[mi][ni] = (f32x4){0.f, 0.f, 0.f, 0.f};

    for (int k0 = 0; k0 < Kd; k0 += 64) {
        // ---- stage A (128 slot-rows x 64 k) ----
#pragma unroll
        for (int i = 0; i < 4; i++) {
            int idx = tid + i * 256;
            int m = idx >> 3, kg = idx & 7;
            int slot = row0 + m;
            bf16x8 v;
            if (slot < cnt) {
                if (AK == 0) {
                    int ri = slot_row[e * NB + slot];
                    const float* p = Af32 + (size_t)ri * lda + k0 + kg * 8;
                    f32x4 f0 = *(const f32x4*)p;
                    f32x4 f1 = *(const f32x4*)(p + 4);
#pragma unroll
                    for (int j = 0; j < 4; j++) { v[j] = (__bf16)f0[j]; v[4 + j] = (__bf16)f1[j]; }
                } else {
                    v = *(const bf16x8*)(Abf + (size_t)(off + slot) * lda + k0 + kg * 8);
                }
            } else {
#pragma unroll
                for (int j = 0; j < 8; j++) v[j] = (__bf16)0.f;
            }
            *(bf16x8*)(sA + m * 128 + ((kg * 16) ^ ((m & 7) << 4))) = v;
        }
        // ---- stage B (64 k x 128 n), f32 -> bf16, to [n][k] ----
#pragma unroll
        for (int i = 0; i < 4; i++) {
            int kg = (tid >> 6) + ((i & 1) << 2);   // 0..7
            int n  = (tid & 63) + ((i >> 1) << 6);  // 0..127
            bf16x8 v;
#pragma unroll
            for (int kk = 0; kk < 8; kk++)
                v[kk] = (__bf16)W[(size_t)(k0 + kg * 8 + kk) * N + n0 + n];
            *(bf16x8*)(sB + n * 128 + ((kg * 16) ^ ((n & 7) << 4))) = v;
        }
        __syncthreads();
        // ---- MFMA: two K=32 steps ----
#pragma unroll
        for (int ks = 0; ks < 2; ks++) {
            bf16x8 af[4], bfr[4];
            const int kb = ks * 64 + ((lane >> 4) << 4);
#pragma unroll
            for (int mi = 0; mi < 4; mi++) {
                int row = wm + mi * 16 + (lane & 15);
                af[mi] = *(const bf16x8*)(sA + row * 128 + (kb ^ ((row & 7) << 4)));
            }
#pragma unroll
            for (int ni = 0; ni < 4; ni++) {
                int row = wn + ni * 16 + (lane & 15);
                bfr[ni] = *(const bf16x8*)(sB + row * 128 + (kb ^ ((row & 7) << 4)));
            }
#pragma unroll
            for (int mi = 0; mi < 4; mi++)
#pragma unroll
                for (int ni = 0; ni < 4; ni++)
                    acc[mi][ni] = __builtin_amdgcn_mfma_f32_16x16x32_bf16(
                        af[mi], bfr[ni], acc[mi][ni], 0, 0, 0);
        }
        __syncthreads();
    }

    // ---- epilogue ----
    const int q = lane >> 4, cl = lane & 15;
#pragma unroll
    for (int mi = 0; mi < 4; mi++) {
#pragma unroll
        for (int r = 0; r < 4; r++) {
            int srow = row0 + wm + mi * 16 + q * 4 + r;
            if (srow >= cnt) continue;
            if (OM == 0) {
#pragma unroll
                for (int ni = 0; ni < 4; ni++) {
                    int col = n0 + wn + ni * 16 + cl;
                    float vv = acc[mi][ni][r] + bias_base[(size_t)e * bias_stride + col];
                    if (ACT) vv = silu_f(vv);
                    outB[(size_t)(off + srow) * N + col] = (__bf16)vv;
                }
            } else {
                int grow = slot_row[e * NB + srow];
                float wsl = slot_w[e * NB + srow];
#pragma unroll
                for (int ni = 0; ni < 4; ni++) {
                    int col = n0 + wn + ni * 16 + cl;
                    atomicAdd(&outF[(size_t)grow * NH + col], wsl * acc[mi][ni][r]);
                }
            }
        }
    }
}

// ---------------------------------------------------------------------------
// Finalize IN-PLACE on f32 out: out = fired ? a*(out/t) + (1-a)*x : x
// ---------------------------------------------------------------------------
__global__ __launch_bounds__(256) void k_final(
    const float* __restrict__ x,
    const float* __restrict__ row_total, const int* __restrict__ row_fired,
    const float* __restrict__ blend, float* __restrict__ out)
{
    int idx = blockIdx.x * 256 + threadIdx.x;  // one thread per 4 elements
    int r = idx >> 8;
    int c = (idx & 255) << 2;
    float alpha = 1.f / (1.f + expf(-blend[0]));
    f32x4 cb = *(const f32x4*)(out + (size_t)r * NH + c);
    f32x4 xv = *(const f32x4*)(x + (size_t)r * NH + c);
    int fired = row_fired[r];
    float inv_t = fired ? (1.f / row_total[r]) : 0.f;
    f32x4 o;
#pragma unroll
    for (int j = 0; j < 4; j++)
        o[j] = fired ? (alpha * (cb[j] * inv_t) + (1.f - alpha) * xv[j]) : xv[j];
    *(f32x4*)&out[(size_t)r * NH + c] = o;
}

// ---------------------------------------------------------------------------
extern "C" void kernel_launch(void* const* d_in, const int* in_sizes, int n_in,
                              void* d_out, int out_size, void* d_ws, size_t ws_size,
                              hipStream_t stream)
{
    float* out_main = (float*)d_out;                      // (B,H) f32
    float* gw_out   = (float*)d_out + (size_t)NB * NH;    // (B,E) f32

    static const long long EXP[11] = {
        (long long)NB * NH, (long long)NH * NG, NG, (long long)NG * NE, NE,
        (long long)NE * NH * NF, (long long)NE * NF,
        (long long)NE * NF * NH, (long long)NE * NH,
        (long long)NE * NH * NH, 1
    };
    bool ok = (n_in == 11);
    if (ok)
        for (int i = 0; i < 11; i++)
            if ((long long)in_sizes[i] != EXP[i]) { ok = false; break; }
    if (!ok) {
        k_sentinel<<<1, 1, 0, stream>>>((float*)d_out, 2000.f + n_in);
        return;
    }

    const float* x    = (const float*)d_in[0];
    const float* gw1  = (const float*)d_in[1];
    const float* gb1  = (const float*)d_in[2];
    const float* gw2  = (const float*)d_in[3];
    const float* gb2  = (const float*)d_in[4];
    const float* ew1  = (const float*)d_in[5];
    const float* eb1  = (const float*)d_in[6];
    const float* ew2  = (const float*)d_in[7];
    const float* eb2  = (const float*)d_in[8];
    const float* pw   = (const float*)d_in[9];
    const float* blnd = (const float*)d_in[10];

    // ---- common small buffers ----
    size_t need = 0;
    size_t off_meta   = need;   need += 512;                   // count[8] + offs[8]
    size_t off_srow   = need;   need += (size_t)NE * NB * 4;
    size_t off_sw     = need;   need += (size_t)NE * NB * 4;
    size_t off_total  = need;   need += (size_t)NB * 4;
    size_t off_fired  = need;   need += (size_t)NB * 4;
    size_t off_hidden = need;   need += (size_t)NB * NG * 4;   // 8 MiB
    size_t off_h1     = need;                                  // H1 starts here

    const size_t MAXSLOTS = (size_t)2 * NB;                    // <= 8192
    size_t need_fast = off_h1 + MAXSLOTS * NF * 2 + MAXSLOTS * NH * 2; // ~88.3 MiB
    size_t need_slow = off_h1 + (size_t)NB * NF * 2 + (size_t)NB * NH * 2; // ~48.3 MiB

    char* ws = (char*)d_ws;
    int*   count     = (int*)(ws + off_meta);
    int*   offs      = count + 8;
    int*   slot_row  = (int*)(ws + off_srow);
    float* slot_w    = (float*)(ws + off_sw);
    float* row_total = (float*)(ws + off_total);
    int*   row_fired = (int*)(ws + off_fired);
    float* hidden    = (float*)(ws + off_hidden);

    const bool fast = (ws_size >= need_fast);
    if (!fast && ws_size < need_slow) {
        k_sentinel<<<1, 1, 0, stream>>>((float*)d_out,
                                        1000.f + (float)(ws_size >> 20));
        return;
    }
    size_t h1_rows = fast ? MAXSLOTS : (size_t)NB;
    __bf16* H1 = (__bf16*)(ws + off_h1);
    __bf16* H2 = (__bf16*)(ws + off_h1 + h1_rows * NF * 2);

    hipMemsetAsync(count, 0, 512, stream);                       // count+offs = 0
    hipMemsetAsync(out_main, 0, (size_t)NB * NH * 4, stream);    // atomic target

    k_gate<<<dim3(NG / 64, NB / 64), 256, 0, stream>>>(x, gw1, gb1, hidden);
    k_router<<<dim3(NB), 64, 0, stream>>>(hidden, gw2, gb2, gw_out,
                                          count, slot_row, slot_w, row_total, row_fired);

    if (fast) {
        k_offsets<<<1, 1, 0, stream>>>(count, offs);
        // FFN1 (all experts): H1[off+slot] = silu(x[slot_row] @ ew1[e] + eb1[e])
        k_moe_gemm<0, 1, 0><<<dim3(NF / 128, NB / 128, NE), 256, 0, stream>>>(
            x, nullptr, NH, ew1, (size_t)NH * NF, eb1, NF,
            H1, nullptr, NF, NH, 0, count, offs, slot_row, slot_w);
        // FFN2 (all experts): H2[off+slot] = H1[off+slot] @ ew2[e] + eb2[e]
        k_moe_gemm<1, 0, 0><<<dim3(NH / 128, NB / 128, NE), 256, 0, stream>>>(
            nullptr, H1, NF, ew2, (size_t)NF * NH, eb2, NH,
            H2, nullptr, NH, NF, 0, count, offs, slot_row, slot_w);
        // PROJ (all experts): out[grow] += slot_w * (H2[off+slot] @ pw[e])
        k_moe_gemm<1, 0, 1><<<dim3(NH / 128, NB / 128, NE), 256, 0, stream>>>(
            nullptr, H2, NH, pw, (size_t)NH * NH, eb2 /*unused*/, 0,
            nullptr, out_main, NH, NH, 0, count, offs, slot_row, slot_w);
    } else {
        // offs stays all-zero: per-expert loop reuses H1/H2 from row 0.
        for (int e = 0; e < NE; e++) {
            k_moe_gemm<0, 1, 0><<<dim3(NF / 128, NB / 128, 1), 256, 0, stream>>>(
                x, nullptr, NH, ew1, (size_t)NH * NF, eb1, NF,
                H1, nullptr, NF, NH, e, count, offs, slot_row, slot_w);
            k_moe_gemm<1, 0, 0><<<dim3(NH / 128, NB / 128, 1), 256, 0, stream>>>(
                nullptr, H1, NF, ew2, (size_t)NF * NH, eb2, NH,
                H2, nullptr, NH, NF, e, count, offs, slot_row, slot_w);
            k_moe_gemm<1, 0, 1><<<dim3(NH / 128, NB / 128, 1), 256, 0, stream>>>(
                nullptr, H2, NH, pw, (size_t)NH * NH, eb2 /*unused*/, 0,
                nullptr, out_main, NH, NH, e, count, offs, slot_row, slot_w);
        }
    }

    k_final<<<dim3(NB * NH / 1024), 256, 0, stream>>>(x, row_total,
                                                      row_fired, blnd, out_main);
}

// Round 11
// 571.750 us; speedup vs baseline: 3.5728x; 1.1426x over previous
//
#include <hip/hip_runtime.h>
#include <hip/hip_bf16.h>
#include <cmath>

constexpr int NB = 4096;   // batch
constexpr int NH = 1024;   // hidden
constexpr int NE = 8;      // experts
constexpr int NF = 4096;   // dff
constexpr int NG = 512;    // gate hidden (H/2)
constexpr float THRESH = 0.1f;
constexpr int PAD_ROWS = 128;
constexpr size_t MAXS = (size_t)2 * NB;        // <= 8192 routed slots
constexpr size_t ROWS = MAXS + PAD_ROWS;       // padded for tile overreach

// Established (rounds 0-10):
//   ALL inputs f32 C-order positional. d_out f32 [output(B,H) | gate_w(B,E)].
//   ws >= ~104 MiB proven. ~All top-2 pass threshold (S ~ 8175 slots).

typedef float  f32x4  __attribute__((ext_vector_type(4)));
typedef __bf16 bf16x8 __attribute__((ext_vector_type(8)));
typedef __bf16 bf16x4 __attribute__((ext_vector_type(4)));

typedef __attribute__((address_space(1))) void gvoid_t;
typedef __attribute__((address_space(3))) void svoid_t;

__device__ __forceinline__ void gl_lds16(const void* g, void* l)
{
    __builtin_amdgcn_global_load_lds((gvoid_t*)g, (svoid_t*)l, 16, 0, 0);
}

__device__ __forceinline__ float silu_f(float v) { return v / (1.f + expf(-v)); }

__global__ void k_sentinel(float* out, float code)
{
    if (threadIdx.x == 0 && blockIdx.x == 0) out[0] = code;
}

// ---------------------------------------------------------------------------
// Transpose+convert one weight family: in f32 [e][R][C] -> out bf16 [e][C][R]
// ---------------------------------------------------------------------------
__global__ __launch_bounds__(256) void k_tconv(
    const float* __restrict__ in, __bf16* __restrict__ out, int R, int C)
{
    __shared__ float t[64][65];
    const int e = blockIdx.z;
    const float* I = in + (size_t)e * R * C;
    __bf16* O = out + (size_t)e * R * C;
    const int r0 = blockIdx.y * 64, c0 = blockIdx.x * 64;
    const int tid = threadIdx.x;
#pragma unroll
    for (int i = 0; i < 16; i++) {
        int idx = tid + i * 256;
        int r = idx >> 6, c = idx & 63;
        t[r][c] = I[(size_t)(r0 + r) * C + c0 + c];
    }
    __syncthreads();
#pragma unroll
    for (int i = 0; i < 16; i++) {
        int idx = tid + i * 256;
        int c = idx >> 6, r = idx & 63;
        O[(size_t)(c0 + c) * R + r0 + r] = (__bf16)t[r][c];
    }
}

// ---------------------------------------------------------------------------
// Gate GEMM: hidden = silu(x @ gate_w1 + gate_b1)   (f32 exact)
// ---------------------------------------------------------------------------
__global__ __launch_bounds__(256) void k_gate(
    const float* __restrict__ x, const float* __restrict__ w1,
    const float* __restrict__ b1, float* __restrict__ hidden)
{
    __shared__ float As[16][68];
    __shared__ float Bs[16][64];
    const int tid = threadIdx.x;
    const int r0 = blockIdx.y * 64, c0 = blockIdx.x * 64;
    const int tx = tid & 15, ty = tid >> 4;
    float acc[4][4] = {};
    for (int k0 = 0; k0 < NH; k0 += 16) {
#pragma unroll
        for (int i = 0; i < 4; i++) {
            int e = tid + i * 256;
            int m = e >> 4, kk = e & 15;
            As[kk][m] = x[(size_t)(r0 + m) * NH + k0 + kk];
        }
#pragma unroll
        for (int i = 0; i < 4; i++) {
            int e = tid + i * 256;
            int kk = e >> 6, n = e & 63;
            Bs[kk][n] = w1[(size_t)(k0 + kk) * NG + c0 + n];
        }
        __syncthreads();
#pragma unroll
        for (int kk = 0; kk < 16; kk++) {
            f32x4 a = *(const f32x4*)&As[kk][ty * 4];
            f32x4 b = *(const f32x4*)&Bs[kk][tx * 4];
#pragma unroll
            for (int i = 0; i < 4; i++)
#pragma unroll
                for (int j = 0; j < 4; j++)
                    acc[i][j] = fmaf(a[i], b[j], acc[i][j]);
        }
        __syncthreads();
    }
#pragma unroll
    for (int i = 0; i < 4; i++) {
        int row = r0 + ty * 4 + i;
        f32x4 o;
#pragma unroll
        for (int j = 0; j < 4; j++)
            o[j] = silu_f(acc[i][j] + b1[c0 + tx * 4 + j]);
        *(f32x4*)&hidden[(size_t)row * NG + c0 + tx * 4] = o;
    }
}

// ---------------------------------------------------------------------------
// Router: softmax -> top2 -> threshold -> per-expert slot lists
// ---------------------------------------------------------------------------
__global__ __launch_bounds__(64) void k_router(
    const float* __restrict__ hidden, const float* __restrict__ w2,
    const float* __restrict__ b2, float* __restrict__ gw_out,
    int* __restrict__ count, int* __restrict__ slot_row,
    float* __restrict__ slot_w, float* __restrict__ row_total,
    int* __restrict__ row_fired)
{
    const int r = blockIdx.x;
    const int l = threadIdx.x;
    float pe[NE] = {};
    for (int k = l; k < NG; k += 64) {
        float h = hidden[(size_t)r * NG + k];
        const float* wr = w2 + (size_t)k * NE;
#pragma unroll
        for (int e = 0; e < NE; e++) pe[e] += h * wr[e];
    }
#pragma unroll
    for (int e = 0; e < NE; e++) {
#pragma unroll
        for (int m = 1; m < 64; m <<= 1) pe[e] += __shfl_xor(pe[e], m);
    }
    float logit[NE];
    float mx = -1e30f;
#pragma unroll
    for (int e = 0; e < NE; e++) { logit[e] = pe[e] + b2[e]; mx = fmaxf(mx, logit[e]); }
    float w[NE], s = 0.f;
#pragma unroll
    for (int e = 0; e < NE; e++) { w[e] = expf(logit[e] - mx); s += w[e]; }
    float inv = 1.f / s;
#pragma unroll
    for (int e = 0; e < NE; e++) w[e] *= inv;
    if (l < NE) gw_out[(size_t)r * NE + l] = w[l];

    int i1 = 0; float v1 = w[0];
#pragma unroll
    for (int e = 1; e < NE; e++) if (w[e] > v1) { v1 = w[e]; i1 = e; }
    int i2 = -1; float v2 = -1.f;
#pragma unroll
    for (int e = 0; e < NE; e++) if (e != i1 && w[e] > v2) { v2 = w[e]; i2 = e; }

    bool k1 = v1 > THRESH, k2 = v2 > THRESH;
    float total = (k1 ? v1 : 0.f) + (k2 ? v2 : 0.f);
    if (l == 0) {
        row_total[r] = total;
        row_fired[r] = (total > 0.f) ? 1 : 0;
        if (k1) { int p = atomicAdd(&count[i1], 1); slot_row[i1 * NB + p] = r; slot_w[i1 * NB + p] = v1; }
        if (k2) { int p = atomicAdd(&count[i2], 1); slot_row[i2 * NB + p] = r; slot_w[i2 * NB + p] = v2; }
    }
}

__global__ void k_offsets(const int* __restrict__ count, int* __restrict__ offs)
{
    if (threadIdx.x == 0 && blockIdx.x == 0) {
        int s = 0;
        for (int e = 0; e < NE; e++) { offs[e] = s; s += count[e]; }
    }
}

// ---------------------------------------------------------------------------
// Compacted bf16 x gather: Xc[slot] = bf16(x[slot_row])
// ---------------------------------------------------------------------------
__global__ __launch_bounds__(256) void k_xc(
    const float* __restrict__ x, const int* __restrict__ count,
    const int* __restrict__ offs, const int* __restrict__ slot_row,
    __bf16* __restrict__ Xc)
{
    const int s = blockIdx.x;
    int e = 0;
#pragma unroll
    for (int i = 1; i < NE; i++) if (s >= offs[i]) e = i;
    if (s >= offs[NE - 1] + count[NE - 1]) return;
    const int r = slot_row[e * NB + (s - offs[e])];
    const float* src = x + (size_t)r * NH;
    __bf16* dst = Xc + (size_t)s * NH;
    const int t = threadIdx.x;
    f32x4 v = *(const f32x4*)(src + t * 4);
    bf16x4 o;
#pragma unroll
    for (int j = 0; j < 4; j++) o[j] = (__bf16)v[j];
    *(bf16x4*)(dst + t * 4) = o;
}

// ---------------------------------------------------------------------------
// TIER A GEMM: both operands bf16 [row][k] contiguous, staged with
// global_load_lds(16B) into linear LDS, XOR-swizzle applied on the global
// source address; ds_read side uses the (proven) swizzled addressing.
// Grid: (X*NE, Y) with e = bx/X, n0 = (bx%X)*128 -> (e,n0) pinned to one XCD.
// OM: 0 = store bf16 compacted rows (+bias), 1 = weighted f32 atomicAdd.
// ---------------------------------------------------------------------------
template<int ACT, int OM>
__global__ __launch_bounds__(256) void k_gemm2(
    const __bf16* __restrict__ A, int lda,
    const __bf16* __restrict__ Wt, size_t wstride,
    const float* __restrict__ bias, int bstride,
    __bf16* __restrict__ outB, float* __restrict__ outF,
    int N, int Kd, int X,
    const int* __restrict__ count, const int* __restrict__ offs,
    const int* __restrict__ slot_row, const float* __restrict__ slot_w)
{
    const int bx = blockIdx.x;
    const int e  = bx / X;
    const int n0 = (bx % X) * 128;
    const int cnt = count[e];
    const int row0 = blockIdx.y * 128;
    if (row0 >= cnt) return;
    const int off = offs[e];
    const __bf16* W = Wt + (size_t)e * wstride;
    const int tid = threadIdx.x;
    const int lane = tid & 63, wid = tid >> 6;
    const int wm = (wid >> 1) * 64, wn = (wid & 1) * 64;
    const int arow0 = off + row0;

    __shared__ __align__(16) unsigned char sA[128 * 128];  // [m][kslot] bf16
    __shared__ __align__(16) unsigned char sB[128 * 128];  // [n][kslot] bf16

    f32x4 acc[4][4];
#pragma unroll
    for (int mi = 0; mi < 4; mi++)
#pragma unroll
        for (int ni = 0; ni < 4; ni++)
            acc[mi][ni] = (f32x4){0.f, 0.f, 0.f, 0.f};

    const int sub = lane >> 3;            // 0..7 row within chunk
    const int kcx = (lane & 7) ^ sub;     // source k-chunk (inverse swizzle)

    for (int k0 = 0; k0 < Kd; k0 += 64) {
#pragma unroll
        for (int i = 0; i < 4; i++) {
            int c = wid * 4 + i;          // chunk 0..15 (8 rows each)
            int row = c * 8 + sub;
            gl_lds16(A + (size_t)(arow0 + row) * lda + k0 + kcx * 8,
                     sA + c * 1024 + lane * 16);
        }
#pragma unroll
        for (int i = 0; i < 4; i++) {
            int c = wid * 4 + i;
            int n = c * 8 + sub;
            gl_lds16(W + (size_t)(n0 + n) * Kd + k0 + kcx * 8,
                     sB + c * 1024 + lane * 16);
        }
        __syncthreads();
#pragma unroll
        for (int ks = 0; ks < 2; ks++) {
            bf16x8 af[4], bfr[4];
            const int kb = ks * 64 + ((lane >> 4) << 4);
#pragma unroll
            for (int mi = 0; mi < 4; mi++) {
                int row = wm + mi * 16 + (lane & 15);
                af[mi] = *(const bf16x8*)(sA + row * 128 + (kb ^ ((row & 7) << 4)));
            }
#pragma unroll
            for (int ni = 0; ni < 4; ni++) {
                int row = wn + ni * 16 + (lane & 15);
                bfr[ni] = *(const bf16x8*)(sB + row * 128 + (kb ^ ((row & 7) << 4)));
            }
#pragma unroll
            for (int mi = 0; mi < 4; mi++)
#pragma unroll
                for (int ni = 0; ni < 4; ni++)
                    acc[mi][ni] = __builtin_amdgcn_mfma_f32_16x16x32_bf16(
                        af[mi], bfr[ni], acc[mi][ni], 0, 0, 0);
        }
        __syncthreads();
    }

    const int q = lane >> 4, cl = lane & 15;
#pragma unroll
    for (int mi = 0; mi < 4; mi++) {
#pragma unroll
        for (int r = 0; r < 4; r++) {
            int srow = row0 + wm + mi * 16 + q * 4 + r;
            if (srow >= cnt) continue;
            if (OM == 0) {
#pragma unroll
                for (int ni = 0; ni < 4; ni++) {
                    int col = n0 + wn + ni * 16 + cl;
                    float vv = acc[mi][ni][r] + bias[(size_t)e * bstride + col];
                    if (ACT) vv = silu_f(vv);
                    outB[(size_t)(off + srow) * N + col] = (__bf16)vv;
                }
            } else {
                int grow = slot_row[e * NB + srow];
                float wsl = slot_w[e * NB + srow];
#pragma unroll
                for (int ni = 0; ni < 4; ni++) {
                    int col = n0 + wn + ni * 16 + cl;
                    atomicAdd(&outF[(size_t)grow * NH + col], wsl * acc[mi][ni][r]);
                }
            }
        }
    }
}

// ---------------------------------------------------------------------------
// TIER B GEMM (round-10 proven reg-staged path, pair-pinned grid decode).
// ---------------------------------------------------------------------------
template<int AK, int ACT, int OM>
__global__ __launch_bounds__(256) void k_gemm1(
    const float* __restrict__ Af32, const __bf16* __restrict__ Abf, int lda,
    const float* __restrict__ Wbase, size_t wstride,
    const float* __restrict__ bias_base, int bias_stride,
    __bf16* __restrict__ outB, float* __restrict__ outF,
    int N, int Kd, int X,
    const int* __restrict__ count, const int* __restrict__ offs,
    const int* __restrict__ slot_row, const float* __restrict__ slot_w)
{
    const int bx = blockIdx.x;
    const int e  = bx / X;
    const int n0 = (bx % X) * 128;
    const int cnt = count[e];
    const int row0 = blockIdx.y * 128;
    if (row0 >= cnt) return;
    const int off = offs[e];
    const float* W = Wbase + (size_t)e * wstride;
    const int tid = threadIdx.x;
    const int lane = tid & 63, wid = tid >> 6;
    const int wm = (wid >> 1) * 64, wn = (wid & 1) * 64;

    __shared__ __align__(16) unsigned char sA[128 * 128];
    __shared__ __align__(16) unsigned char sB[128 * 128];

    f32x4 acc[4][4];
#pragma unroll
    for (int mi = 0; mi < 4; mi++)
#pragma unroll
        for (int ni = 0; ni < 4; ni++)
            acc[mi][ni] = (f32x4){0.f, 0.f, 0.f, 0.f};

    for (int k0 = 0; k0 < Kd; k0 += 64) {
#pragma unroll
        for (int i = 0; i < 4; i++) {
            int idx = tid + i * 256;
            int m = idx >> 3, kg = idx & 7;
            int slot = row0 + m;
            bf16x8 v;
            if (slot < cnt) {
                if (AK == 0) {
                    int ri = slot_row[e * NB + slot];
                    const float* p = Af32 + (size_t)ri * lda + k0 + kg * 8;
                    f32x4 f0 = *(const f32x4*)p;
                    f32x4 f1 = *(const f32x4*)(p + 4);
#pragma unroll
                    for (int j = 0; j < 4; j++) { v[j] = (__bf16)f0[j]; v[4 + j] = (__bf16)f1[j]; }
                } else {
                    v = *(const bf16x8*)(Abf + (size_t)(off + slot) * lda + k0 + kg * 8);
                }
            } else {
#pragma unroll
                for (int j = 0; j < 8; j++) v[j] = (__bf16)0.f;
            }
            *(bf16x8*)(sA + m * 128 + ((kg * 16) ^ ((m & 7) << 4))) = v;
        }
#pragma unroll
        for (int i = 0; i < 4; i++) {
            int kg = (tid >> 6) + ((i & 1) << 2);
            int n  = (tid & 63) + ((i >> 1) << 6);
            bf16x8 v;
#pragma unroll
            for (int kk = 0; kk < 8; kk++)
                v[kk] = (__bf16)W[(size_t)(k0 + kg * 8 + kk) * N + n0 + n];
            *(bf16x8*)(sB + n * 128 + ((kg * 16) ^ ((n & 7) << 4))) = v;
        }
        __syncthreads();
#pragma unroll
        for (int ks = 0; ks < 2; ks++) {
            bf16x8 af[4], bfr[4];
            const int kb = ks * 64 + ((lane >> 4) << 4);
#pragma unroll
            for (int mi = 0; mi < 4; mi++) {
                int row = wm + mi * 16 + (lane & 15);
                af[mi] = *(const bf16x8*)(sA + row * 128 + (kb ^ ((row & 7) << 4)));
            }
#pragma unroll
            for (int ni = 0; ni < 4; ni++) {
                int row = wn + ni * 16 + (lane & 15);
                bfr[ni] = *(const bf16x8*)(sB + row * 128 + (kb ^ ((row & 7) << 4)));
            }
#pragma unroll
            for (int mi = 0; mi < 4; mi++)
#pragma unroll
                for (int ni = 0; ni < 4; ni++)
                    acc[mi][ni] = __builtin_amdgcn_mfma_f32_16x16x32_bf16(
                        af[mi], bfr[ni], acc[mi][ni], 0, 0, 0);
        }
        __syncthreads();
    }

    const int q = lane >> 4, cl = lane & 15;
#pragma unroll
    for (int mi = 0; mi < 4; mi++) {
#pragma unroll
        for (int r = 0; r < 4; r++) {
            int srow = row0 + wm + mi * 16 + q * 4 + r;
            if (srow >= cnt) continue;
            if (OM == 0) {
#pragma unroll
                for (int ni = 0; ni < 4; ni++) {
                    int col = n0 + wn + ni * 16 + cl;
                    float vv = acc[mi][ni][r] + bias_base[(size_t)e * bias_stride + col];
                    if (ACT) vv = silu_f(vv);
                    outB[(size_t)(off + srow) * N + col] = (__bf16)vv;
                }
            } else {
                int grow = slot_row[e * NB + srow];
                float wsl = slot_w[e * NB + srow];
#pragma unroll
                for (int ni = 0; ni < 4; ni++) {
                    int col = n0 + wn + ni * 16 + cl;
                    atomicAdd(&outF[(size_t)grow * NH + col], wsl * acc[mi][ni][r]);
                }
            }
        }
    }
}

// ---------------------------------------------------------------------------
// Finalize IN-PLACE: out = fired ? a*(out/t) + (1-a)*x : x
// ---------------------------------------------------------------------------
__global__ __launch_bounds__(256) void k_final(
    const float* __restrict__ x,
    const float* __restrict__ row_total, const int* __restrict__ row_fired,
    const float* __restrict__ blend, float* __restrict__ out)
{
    int idx = blockIdx.x * 256 + threadIdx.x;
    int r = idx >> 8;
    int c = (idx & 255) << 2;
    float alpha = 1.f / (1.f + expf(-blend[0]));
    f32x4 cb = *(const f32x4*)(out + (size_t)r * NH + c);
    f32x4 xv = *(const f32x4*)(x + (size_t)r * NH + c);
    int fired = row_fired[r];
    float inv_t = fired ? (1.f / row_total[r]) : 0.f;
    f32x4 o;
#pragma unroll
    for (int j = 0; j < 4; j++)
        o[j] = fired ? (alpha * (cb[j] * inv_t) + (1.f - alpha) * xv[j]) : xv[j];
    *(f32x4*)&out[(size_t)r * NH + c] = o;
}

// ---------------------------------------------------------------------------
extern "C" void kernel_launch(void* const* d_in, const int* in_sizes, int n_in,
                              void* d_out, int out_size, void* d_ws, size_t ws_size,
                              hipStream_t stream)
{
    float* out_main = (float*)d_out;
    float* gw_out   = (float*)d_out + (size_t)NB * NH;

    static const long long EXP[11] = {
        (long long)NB * NH, (long long)NH * NG, NG, (long long)NG * NE, NE,
        (long long)NE * NH * NF, (long long)NE * NF,
        (long long)NE * NF * NH, (long long)NE * NH,
        (long long)NE * NH * NH, 1
    };
    bool ok = (n_in == 11);
    if (ok)
        for (int i = 0; i < 11; i++)
            if ((long long)in_sizes[i] != EXP[i]) { ok = false; break; }
    if (!ok) {
        k_sentinel<<<1, 1, 0, stream>>>((float*)d_out, 2000.f + n_in);
        return;
    }

    const float* x    = (const float*)d_in[0];
    const float* gw1  = (const float*)d_in[1];
    const float* gb1  = (const float*)d_in[2];
    const float* gw2  = (const float*)d_in[3];
    const float* gb2  = (const float*)d_in[4];
    const float* ew1  = (const float*)d_in[5];
    const float* eb1  = (const float*)d_in[6];
    const float* ew2  = (const float*)d_in[7];
    const float* eb2  = (const float*)d_in[8];
    const float* pw   = (const float*)d_in[9];
    const float* blnd = (const float*)d_in[10];

    // ---- common small buffers ----
    size_t need = 0;
    size_t off_meta   = need;   need += 512;
    size_t off_srow   = need;   need += (size_t)NE * NB * 4;
    size_t off_sw     = need;   need += (size_t)NE * NB * 4;
    size_t off_total  = need;   need += (size_t)NB * 4;
    size_t off_fired  = need;   need += (size_t)NB * 4;
    size_t off_hidden = need;   need += (size_t)NB * NG * 4;
    size_t base = need;

    // Tier A layout
    size_t a_xc  = base;
    size_t a_h1  = a_xc + ROWS * NH * 2;
    size_t a_h2  = a_h1 + ROWS * NF * 2;
    size_t a_w1  = a_h2 + ROWS * NH * 2;
    size_t a_w2  = a_w1 + (size_t)NE * NH * NF * 2;
    size_t a_wp  = a_w2 + (size_t)NE * NF * NH * 2;
    size_t need_A = a_wp + (size_t)NE * NH * NH * 2;   // ~250 MiB

    // Tier B layout (round-10)
    size_t b_h1 = base;
    size_t b_h2 = b_h1 + MAXS * NF * 2;
    size_t need_B = b_h2 + MAXS * NH * 2;              // ~88.3 MiB

    char* ws = (char*)d_ws;
    int*   count     = (int*)(ws + off_meta);
    int*   offs      = count + 8;
    int*   slot_row  = (int*)(ws + off_srow);
    float* slot_w    = (float*)(ws + off_sw);
    float* row_total = (float*)(ws + off_total);
    int*   row_fired = (int*)(ws + off_fired);
    float* hidden    = (float*)(ws + off_hidden);

    const bool tierA = (ws_size >= need_A);
    if (!tierA && ws_size < need_B) {
        k_sentinel<<<1, 1, 0, stream>>>((float*)d_out,
                                        1000.f + (float)(ws_size >> 20));
        return;
    }

    hipMemsetAsync(count, 0, 512, stream);
    hipMemsetAsync(out_main, 0, (size_t)NB * NH * 4, stream);

    k_gate<<<dim3(NG / 64, NB / 64), 256, 0, stream>>>(x, gw1, gb1, hidden);
    k_router<<<dim3(NB), 64, 0, stream>>>(hidden, gw2, gb2, gw_out,
                                          count, slot_row, slot_w, row_total, row_fired);
    k_offsets<<<1, 1, 0, stream>>>(count, offs);

    if (tierA) {
        __bf16* Xc  = (__bf16*)(ws + a_xc);
        __bf16* H1  = (__bf16*)(ws + a_h1);
        __bf16* H2  = (__bf16*)(ws + a_h2);
        __bf16* Wt1 = (__bf16*)(ws + a_w1);
        __bf16* Wt2 = (__bf16*)(ws + a_w2);
        __bf16* Wtp = (__bf16*)(ws + a_wp);

        // Weight transpose+convert: ew1[NH][NF]->Wt1[NF][NH], etc.
        k_tconv<<<dim3(NF / 64, NH / 64, NE), 256, 0, stream>>>(ew1, Wt1, NH, NF);
        k_tconv<<<dim3(NH / 64, NF / 64, NE), 256, 0, stream>>>(ew2, Wt2, NF, NH);
        k_tconv<<<dim3(NH / 64, NH / 64, NE), 256, 0, stream>>>(pw,  Wtp, NH, NH);
        k_xc<<<dim3((int)MAXS), 256, 0, stream>>>(x, count, offs, slot_row, Xc);

        // FFN1: H1 = silu(Xc @ ew1 + eb1)      X = NF/128 = 32
        k_gemm2<1, 0><<<dim3(32 * NE, NB / 128), 256, 0, stream>>>(
            Xc, NH, Wt1, (size_t)NH * NF, eb1, NF,
            H1, nullptr, NF, NH, 32, count, offs, slot_row, slot_w);
        // FFN2: H2 = H1 @ ew2 + eb2            X = NH/128 = 8
        k_gemm2<0, 0><<<dim3(8 * NE, NB / 128), 256, 0, stream>>>(
            H1, NF, Wt2, (size_t)NF * NH, eb2, NH,
            H2, nullptr, NH, NF, 8, count, offs, slot_row, slot_w);
        // PROJ: out += slot_w * (H2 @ pw)      X = 8
        k_gemm2<0, 1><<<dim3(8 * NE, NB / 128), 256, 0, stream>>>(
            H2, NH, Wtp, (size_t)NH * NH, eb2 /*unused*/, 0,
            nullptr, out_main, NH, NH, 8, count, offs, slot_row, slot_w);
    } else {
        __bf16* H1 = (__bf16*)(ws + b_h1);
        __bf16* H2 = (__bf16*)(ws + b_h2);

        k_gemm1<0, 1, 0><<<dim3(32 * NE, NB / 128), 256, 0, stream>>>(
            x, nullptr, NH, ew1, (size_t)NH * NF, eb1, NF,
            H1, nullptr, NF, NH, 32, count, offs, slot_row, slot_w);
        k_gemm1<1, 0, 0><<<dim3(8 * NE, NB / 128), 256, 0, stream>>>(
            nullptr, H1, NF, ew2, (size_t)NF * NH, eb2, NH,
            H2, nullptr, NH, NF, 8, count, offs, slot_row, slot_w);
        k_gemm1<1, 0, 1><<<dim3(8 * NE, NB / 128), 256, 0, stream>>>(
            nullptr, H2, NH, pw, (size_t)NH * NH, eb2 /*unused*/, 0,
            nullptr, out_main, NH, NH, 8, count, offs, slot_row, slot_w);
    }

    k_final<<<dim3(NB * NH / 1024), 256, 0, stream>>>(x, row_total,
                                                      row_fired, blnd, out_main);
}